// Round 3
// 245.633 us; speedup vs baseline: 1.0078x; 1.0078x over previous
//
#include <hip/hip_runtime.h>
#include <math.h>

// LSQ quantizer with Hadamard rotation via FWHT:
//   out_row = FWHT( h0 .* s .* rint(clamp(FWHT(x_row) .* h0 / s, -Qn, Qp)) )
// with h0 = hadamard[0,:] = signs/sqrt(D).
//
// Round-4: lane-bit butterflies for j5/j6/j7 via v_permlane{16,32}_swap_b32.
// The exact swap semantics (which halves exchange; builtin result order) have
// 4 plausible variants -- a wave-uniform runtime PROBE classifies the actual
// hardware behavior and selects the matching butterfly code; if none matches,
// a known-correct __shfl_xor fallback is used. Correct under all hypotheses.
//
// Bit partition of element index j (11 bits):
//   layout A: comps=j[0:2], lanes=j[2:8] (lane bit k = j[k+2]), regs=j[8:11]
//             -> VALU: comps {0,1}, regs {8,9,10}, perm16 = j6, perm32 = j7
//   layout B: comps=j[0:2], regs=j[2:5], lanes: bit5=j5, bits0..4=j[6:11]
//             -> VALU: regs {2,3,4}, perm32 = j5
// LDS swizzle on the linear float address a: a ^= ((a>>6)&7)<<2.
// (element-traced: write/read addresses consistent; 8 lanes/bank per b128 op)

constexpr int D  = 2048;
constexpr int NR = 8;   // float4 regs per lane: 8 * 4 * 64 = 2048

#define LGKM0() __asm__ __volatile__("s_waitcnt lgkmcnt(0)" ::: "memory")

typedef unsigned uint2v __attribute__((ext_vector_type(2)));

__device__ __forceinline__ void bfly(float4& a, float4& b) {
    float4 ta = a, tb = b;
    a.x = ta.x + tb.x; a.y = ta.y + tb.y; a.z = ta.z + tb.z; a.w = ta.w + tb.w;
    b.x = ta.x - tb.x; b.y = ta.y - tb.y; b.z = ta.z - tb.z; b.w = ta.w - tb.w;
}

__device__ __forceinline__ void reg_stages(float4 (&v)[NR]) {
    #pragma unroll
    for (int m = 1; m <= 4; m <<= 1) {
        #pragma unroll
        for (int r = 0; r < NR; ++r)
            if ((r & m) == 0) bfly(v[r], v[r | m]);
    }
}

__device__ __forceinline__ void comp_stages(float4 (&v)[NR]) {
    #pragma unroll
    for (int r = 0; r < NR; ++r) {
        float a, b;
        a = v[r].x; b = v[r].y; v[r].x = a + b; v[r].y = a - b;   // bit 0
        a = v[r].z; b = v[r].w; v[r].z = a + b; v[r].w = a - b;
        a = v[r].x; b = v[r].z; v[r].x = a + b; v[r].z = a - b;   // bit 1
        a = v[r].y; b = v[r].w; v[r].y = a + b; v[r].w = a - b;
    }
}

// ---- raw permlane swaps (semantics probed at runtime) ----
__device__ __forceinline__ void plswap32(float& x, float& y) {
#if __has_builtin(__builtin_amdgcn_permlane32_swap)
    uint2v t = __builtin_amdgcn_permlane32_swap(
        __builtin_bit_cast(unsigned, x), __builtin_bit_cast(unsigned, y),
        false, false);
    x = __builtin_bit_cast(float, t[0]);
    y = __builtin_bit_cast(float, t[1]);
#else
    asm volatile("v_permlane32_swap_b32 %0, %1" : "+v"(x), "+v"(y));
#endif
}
__device__ __forceinline__ void plswap16(float& x, float& y) {
#if __has_builtin(__builtin_amdgcn_permlane16_swap)
    uint2v t = __builtin_amdgcn_permlane16_swap(
        __builtin_bit_cast(unsigned, x), __builtin_bit_cast(unsigned, y),
        false, false);
    x = __builtin_bit_cast(float, t[0]);
    y = __builtin_bit_cast(float, t[1]);
#else
    asm volatile("v_permlane16_swap_b32 %0, %1" : "+v"(x), "+v"(y));
#endif
}

// Probe: classify actual swap semantics into variant 0..3 (4 = unknown).
// Variant meaning for plswap(a,b) with group size m:
//   0: a <- [a_lo,b_lo], b <- [a_hi,b_hi]   (per m-group pair)
//   1: a <- [a_hi,b_hi], b <- [a_lo,b_lo]
//   2: a <- [b_hi,a_hi], b <- [b_lo,a_lo]
//   3: a <- [b_lo,a_lo], b <- [b_hi,a_hi]
template<bool IS32>
__device__ __forceinline__ int probe_var(int lane) {
    const int m = IS32 ? 32 : 16;
    float a = (float)lane, b = 1000.0f + (float)lane;
    if (IS32) plswap32(a, b); else plswap16(a, b);
    const bool hi = (lane & m) != 0;
    const float ea0 = hi ? 1000.0f + (float)(lane - m) : (float)lane;
    const float eb0 = hi ? 1000.0f + (float)lane       : (float)(lane + m);
    const float ea2 = hi ? (float)lane                 : 1000.0f + (float)(lane + m);
    const float eb2 = hi ? (float)(lane - m)           : 1000.0f + (float)lane;
    if (__all(a == ea0 && b == eb0)) return 0;
    if (__all(a == eb0 && b == ea0)) return 1;
    if (__all(a == ea2 && b == eb2)) return 2;
    if (__all(a == eb2 && b == ea2)) return 3;
    return 4;
}

// Lane butterfly on group-bit m for TWO registers at once, per probed variant.
// Each derived so that final a=[sum_a,diff_a], b=[sum_b,diff_b] (diff = lo-hi).
template<int VAR, bool IS32>
__device__ __forceinline__ void bfly_l(float& a, float& b) {
    if (IS32) plswap32(a, b); else plswap16(a, b);
    float s = a + b;
    float d = (VAR == 0 || VAR == 3) ? (a - b) : (b - a);
    if (VAR == 0)      { if (IS32) plswap32(s, d); else plswap16(s, d); a = s; b = d; }
    else if (VAR == 1) { if (IS32) plswap32(s, d); else plswap16(s, d); a = d; b = s; }
    else if (VAR == 2) { if (IS32) plswap32(d, s); else plswap16(d, s); a = d; b = s; }
    else               { if (IS32) plswap32(d, s); else plswap16(d, s); a = s; b = d; }
}

template<int VAR, bool IS32>
__device__ __forceinline__ void perm_stage_t(float4 (&v)[NR]) {
    #pragma unroll
    for (int r = 0; r < NR; r += 2) {
        bfly_l<VAR, IS32>(v[r].x, v[r + 1].x);
        bfly_l<VAR, IS32>(v[r].y, v[r + 1].y);
        bfly_l<VAR, IS32>(v[r].z, v[r + 1].z);
        bfly_l<VAR, IS32>(v[r].w, v[r + 1].w);
    }
}

// Known-correct fallback: xor-m butterfly via ds_bpermute shuffle.
__device__ __forceinline__ void shfl_stage(float4 (&v)[NR], int m, int lane) {
    const bool hi = (lane & m) != 0;
    #pragma unroll
    for (int r = 0; r < NR; ++r) {
        float t;
        t = __shfl_xor(v[r].x, m); v[r].x = hi ? t - v[r].x : v[r].x + t;
        t = __shfl_xor(v[r].y, m); v[r].y = hi ? t - v[r].y : v[r].y + t;
        t = __shfl_xor(v[r].z, m); v[r].z = hi ? t - v[r].z : v[r].z + t;
        t = __shfl_xor(v[r].w, m); v[r].w = hi ? t - v[r].w : v[r].w + t;
    }
}

template<bool IS32>
__device__ __forceinline__ void perm_stage(float4 (&v)[NR], int var, int lane) {
    switch (var) {
    case 0: perm_stage_t<0, IS32>(v); break;
    case 1: perm_stage_t<1, IS32>(v); break;
    case 2: perm_stage_t<2, IS32>(v); break;
    case 3: perm_stage_t<3, IS32>(v); break;
    default: shfl_stage(v, IS32 ? 32 : 16, lane); break;
    }
}

__device__ __forceinline__ float quant1(float xh, float h0, float s, float inv_s,
                                        float nqn, float qp) {
    float u = xh * h0 * inv_s;
    u = fminf(fmaxf(u, nqn), qp);
    float q = rintf(u);                       // round half-to-even (jnp.round)
    return q * (s * h0);                      // *s, fold the second h0 multiply
}

__global__ __launch_bounds__(256) void lsq_fwht_kernel(
    const float* __restrict__ x,
    const float* __restrict__ scale,
    const float* __restrict__ hadamard,
    const int*   __restrict__ qn_p,
    const int*   __restrict__ qp_p,
    const int*   __restrict__ ne_p,
    float*       __restrict__ out,
    int rows)
{
    __shared__ float smem[4][D];              // 8 KiB per wave, wave-private

    const int lane = threadIdx.x & 63;
    const int wave = threadIdx.x >> 6;
    const int row  = blockIdx.x * 4 + wave;   // one wave per row
    if (row >= rows) return;

    float* lds = smem[wave];

    // probe permlane swap semantics (wave-uniform, ~20 instrs, once per wave)
    const int v32 = probe_var<true>(lane);
    const int v16 = probe_var<false>(lane);

    // LSQ scale trick (forward value == scale), fp32 rounding as in reference
    const float sc    = scale[0];
    const float qp    = (float)qp_p[0];
    const float nqn   = -(float)qn_p[0];
    const float gs    = 1.0f / sqrtf((float)ne_p[0] * qp);
    const float bw    = sc * gs;
    const float s     = (sc - bw) + bw;
    const float inv_s = 1.0f / s;

    // ---- load x in layout A: j = r*256 + lane*4 + c (coalesced) ----
    float4 v[NR];
    {
        const float4* x4 = reinterpret_cast<const float4*>(x + (size_t)row * D) + lane;
        #pragma unroll
        for (int r = 0; r < NR; ++r) v[r] = x4[(size_t)r * 64];
    }

    // ---- layout-B base: j = c + q*4 + ((lane>>5)&1)*32 + (lane&31)*64 ----
    const int rB0 = (((lane >> 5) & 1) << 5) + ((lane & 31) << 6);

    // ---- load h0 in layout B ----
    float4 h[NR];
    {
        const float* hp = hadamard + rB0;
        #pragma unroll
        for (int q = 0; q < NR; ++q)
            h[q] = *reinterpret_cast<const float4*>(hp + (q << 2));
    }

    // A-side swizzled float4 base: (r<<8) + (wA0 ^ ((r&1)<<4))
    const int wA0 = (lane << 2) ^ (((lane >> 4) & 3) << 2);
    const int l7s = (lane & 7) << 2;          // B-side swizzle term

    // ================= FWHT #1 =================
    comp_stages(v);                                         // bits 0,1
    reg_stages(v);                                          // bits 8,9,10
    perm_stage<false>(v, v16, lane);                        // bit 6 (lane^16)
    perm_stage<true >(v, v32, lane);                        // bit 7 (lane^32)
    // transpose A -> B
    #pragma unroll
    for (int r = 0; r < NR; ++r)
        *reinterpret_cast<float4*>(lds + (r << 8) + (wA0 ^ ((r & 1) << 4))) = v[r];
    LGKM0();
    #pragma unroll
    for (int q = 0; q < NR; ++q)
        v[q] = *reinterpret_cast<const float4*>(lds + rB0 + ((q << 2) ^ l7s));
    reg_stages(v);                                          // bits 2,3,4
    perm_stage<true >(v, v32, lane);                        // bit 5 (lane^32)

    // ================= quantize (layout B) =================
    #pragma unroll
    for (int r = 0; r < NR; ++r) {
        v[r].x = quant1(v[r].x, h[r].x, s, inv_s, nqn, qp);
        v[r].y = quant1(v[r].y, h[r].y, s, inv_s, nqn, qp);
        v[r].z = quant1(v[r].z, h[r].z, s, inv_s, nqn, qp);
        v[r].w = quant1(v[r].w, h[r].w, s, inv_s, nqn, qp);
    }

    // ================= FWHT #2 =================
    reg_stages(v);                                          // bits 2,3,4
    perm_stage<true >(v, v32, lane);                        // bit 5
    // transpose B -> A
    #pragma unroll
    for (int q = 0; q < NR; ++q)
        *reinterpret_cast<float4*>(lds + rB0 + ((q << 2) ^ l7s)) = v[q];
    LGKM0();
    #pragma unroll
    for (int r = 0; r < NR; ++r)
        v[r] = *reinterpret_cast<const float4*>(lds + (r << 8) + (wA0 ^ ((r & 1) << 4)));
    reg_stages(v);                                          // bits 8,9,10
    perm_stage<false>(v, v16, lane);                        // bit 6
    perm_stage<true >(v, v32, lane);                        // bit 7
    comp_stages(v);                                         // bits 0,1

    // ---- store (layout A, coalesced) ----
    {
        float4* y4 = reinterpret_cast<float4*>(out + (size_t)row * D) + lane;
        #pragma unroll
        for (int r = 0; r < NR; ++r) y4[(size_t)r * 64] = v[r];
    }
}

extern "C" void kernel_launch(void* const* d_in, const int* in_sizes, int n_in,
                              void* d_out, int out_size, void* d_ws, size_t ws_size,
                              hipStream_t stream) {
    const float* x        = (const float*)d_in[0];
    const float* scale    = (const float*)d_in[1];
    const float* hadamard = (const float*)d_in[2];
    const int*   Qn       = (const int*)d_in[3];
    const int*   Qp       = (const int*)d_in[4];
    const int*   ne       = (const int*)d_in[5];
    float*       out      = (float*)d_out;

    const int rows = in_sizes[0] / D;          // 16384 for B=4,S=4096
    const int grid = (rows + 3) / 4;           // 4 waves (rows) per block

    lsq_fwht_kernel<<<grid, 256, 0, stream>>>(x, scale, hadamard, Qn, Qp, ne,
                                              out, rows);
}